// Round 1
// baseline (57.567 us; speedup 1.0000x reference)
//
#include <hip/hip_runtime.h>
#include <math.h>

// Problem constants (D_IN == D_OUT == 4096)
constexpr int   D     = 4096;
constexpr float ALPHA = 0.001f;   // heb_lr
constexpr float GAMMA = 0.99f;
constexpr float EPSC  = 0.0001f;

// Scan decomposition
constexpr int CHUNK          = 32;             // rows per chunk
constexpr int NCHUNK         = D / CHUNK;      // 128
constexpr int TPB            = 256;
constexpr int COLS_PER_BLOCK = TPB * 4;        // 1024 (float4 per thread)
constexpr int NCOLTILE       = D / COLS_PER_BLOCK; // 4

// ---------------------------------------------------------------------------
// Kernel 1: u = W @ x + b   (one wave per row, float4 coalesced)
// ---------------------------------------------------------------------------
__global__ __launch_bounds__(256) void k_gemv(const float* __restrict__ W,
                                              const float* __restrict__ x,
                                              const float* __restrict__ b,
                                              float* __restrict__ u) {
    const int wave = threadIdx.x >> 6;        // 0..3
    const int lane = threadIdx.x & 63;
    const int row  = (blockIdx.x << 2) + wave;
    const float4* Wr = reinterpret_cast<const float4*>(W + (size_t)row * D);
    const float4* xv = reinterpret_cast<const float4*>(x);
    float acc = 0.f;
    #pragma unroll
    for (int it = 0; it < D / 256; ++it) {    // 16 iterations: 64 lanes x float4
        const float4 w  = Wr[lane + it * 64];
        const float4 xx = xv[lane + it * 64];
        acc += w.x * xx.x + w.y * xx.y + w.z * xx.z + w.w * xx.w;
    }
    #pragma unroll
    for (int off = 32; off; off >>= 1) acc += __shfl_down(acc, off, 64);
    if (lane == 0) u[row] = acc + b[row];
}

// ---------------------------------------------------------------------------
// Kernel 2 (single block): m = max(relu(u)); y = r^2/m^2; exp_avg update;
// avg = mean(exp_avg_new); gf_pos/gf_neg per row.
// ---------------------------------------------------------------------------
__global__ __launch_bounds__(1024) void k_stats(const float* __restrict__ u,
                                                const float* __restrict__ ea_in,
                                                float* __restrict__ y_out,
                                                float* __restrict__ ea_out,
                                                float* __restrict__ gfp,
                                                float* __restrict__ gfn) {
    __shared__ float sred[16];
    const int tid = threadIdx.x;

    float r[4];
    float lmax = 0.f;
    #pragma unroll
    for (int i = 0; i < 4; ++i) {
        float v = u[tid + i * 1024];
        v = fmaxf(v, 0.f);
        r[i] = v;
        lmax = fmaxf(lmax, v);
    }
    #pragma unroll
    for (int off = 32; off; off >>= 1) lmax = fmaxf(lmax, __shfl_down(lmax, off, 64));
    if ((tid & 63) == 0) sred[tid >> 6] = lmax;
    __syncthreads();
    if (tid == 0) {
        float v = sred[0];
        #pragma unroll
        for (int i = 1; i < 16; ++i) v = fmaxf(v, sred[i]);
        sred[0] = v;
    }
    __syncthreads();
    const float m = sred[0];
    const float inv_m2 = 1.f / (m * m);

    float e[4];
    float lsum = 0.f;
    #pragma unroll
    for (int i = 0; i < 4; ++i) {
        const int idx = tid + i * 1024;
        const float yv = r[i] * r[i] * inv_m2;   // r^LAMB / m^LAMB, LAMB=2
        y_out[idx] = yv;
        const float ev = GAMMA * ea_in[idx] + (1.f - GAMMA) * yv;
        ea_out[idx] = ev;
        e[i] = ev;
        lsum += ev;
    }
    #pragma unroll
    for (int off = 32; off; off >>= 1) lsum += __shfl_down(lsum, off, 64);
    __syncthreads();                     // protect sred reuse (m reads done)
    if ((tid & 63) == 0) sred[tid >> 6] = lsum;
    __syncthreads();
    if (tid == 0) {
        float v = 0.f;
        #pragma unroll
        for (int i = 0; i < 16; ++i) v += sred[i];
        sred[0] = v;
    }
    __syncthreads();
    const float inv_avg = (float)D / sred[0];
    #pragma unroll
    for (int i = 0; i < 4; ++i) {
        const int idx = tid + i * 1024;
        const float a = e[i] * inv_avg;
        const float g = EPSC * tanhf(-EPSC * (a - 1.f)) + 1.f;
        gfp[idx] = g;
        gfn[idx] = 1.f / g;
    }
}

// ---------------------------------------------------------------------------
// Kernel 3: per-chunk column partial sums  P[c,j] = sum_{k in chunk c} y[k]*W[k,j]
// ---------------------------------------------------------------------------
__global__ __launch_bounds__(256) void k_partial(const float* __restrict__ W,
                                                 const float* __restrict__ y,
                                                 float* __restrict__ P) {
    const int j  = blockIdx.x * COLS_PER_BLOCK + threadIdx.x * 4;
    const int c  = blockIdx.y;
    const int k0 = c * CHUNK;
    const float4* Wp = reinterpret_cast<const float4*>(W + (size_t)k0 * D + j);
    float4 acc = make_float4(0.f, 0.f, 0.f, 0.f);
    #pragma unroll 8
    for (int k = 0; k < CHUNK; ++k) {
        const float yv = y[k0 + k];
        const float4 w = Wp[(size_t)k * (D / 4)];
        acc.x += yv * w.x; acc.y += yv * w.y;
        acc.z += yv * w.z; acc.w += yv * w.w;
    }
    *reinterpret_cast<float4*>(P + (size_t)c * D + j) = acc;
}

// ---------------------------------------------------------------------------
// Kernel 4: in-place EXCLUSIVE scan over chunks (per column), double accum.
// One thread per column; coalesced across c-rows of P.
// ---------------------------------------------------------------------------
__global__ __launch_bounds__(256) void k_scan(float* __restrict__ P) {
    const int j = blockIdx.x * blockDim.x + threadIdx.x;
    double acc = 0.0;
    for (int c = 0; c < NCHUNK; ++c) {
        float* p = P + (size_t)c * D + j;
        const float t = *p;
        *p = (float)acc;
        acc += (double)t;
    }
}

// ---------------------------------------------------------------------------
// Kernel 5: resume inclusive scan within chunk; fuse Hebbian delta + decay.
//   S[l,j] = base + sum_{k0<=k<=l} y[k] W[k,j]
//   w1 = W + ALPHA*(y[l]*x[j] - y[l]*S[l,j])
//   w2 = w1>0 ? w1*gf_pos[l] : (w1<0 ? w1*gf_neg[l] : 0)
// ---------------------------------------------------------------------------
__global__ __launch_bounds__(256) void k_update(const float* __restrict__ W,
                                                const float* __restrict__ x,
                                                const float* __restrict__ y,
                                                const float* __restrict__ Pex,
                                                const float* __restrict__ gfp,
                                                const float* __restrict__ gfn,
                                                float* __restrict__ W2) {
    const int j  = blockIdx.x * COLS_PER_BLOCK + threadIdx.x * 4;
    const int c  = blockIdx.y;
    const int k0 = c * CHUNK;
    float4 s = *reinterpret_cast<const float4*>(Pex + (size_t)c * D + j);
    const float4 xv = *reinterpret_cast<const float4*>(x + j);
    const float4* Wp  = reinterpret_cast<const float4*>(W + (size_t)k0 * D + j);
    float4*       W2p = reinterpret_cast<float4*>(W2 + (size_t)k0 * D + j);
    for (int k = 0; k < CHUNK; ++k) {
        const int row = k0 + k;
        const float yv = y[row];
        const float gp = gfp[row];
        const float gn = gfn[row];
        const float4 w = Wp[(size_t)k * (D / 4)];
        s.x += yv * w.x; s.y += yv * w.y;
        s.z += yv * w.z; s.w += yv * w.w;
        float4 o;
        {
            const float w1 = w.x + ALPHA * (yv * xv.x - yv * s.x);
            o.x = w1 > 0.f ? w1 * gp : (w1 < 0.f ? w1 * gn : 0.f);
        }
        {
            const float w1 = w.y + ALPHA * (yv * xv.y - yv * s.y);
            o.y = w1 > 0.f ? w1 * gp : (w1 < 0.f ? w1 * gn : 0.f);
        }
        {
            const float w1 = w.z + ALPHA * (yv * xv.z - yv * s.z);
            o.z = w1 > 0.f ? w1 * gp : (w1 < 0.f ? w1 * gn : 0.f);
        }
        {
            const float w1 = w.w + ALPHA * (yv * xv.w - yv * s.w);
            o.w = w1 > 0.f ? w1 * gp : (w1 < 0.f ? w1 * gn : 0.f);
        }
        W2p[(size_t)k * (D / 4)] = o;
    }
}

// ---------------------------------------------------------------------------
extern "C" void kernel_launch(void* const* d_in, const int* in_sizes, int n_in,
                              void* d_out, int out_size, void* d_ws, size_t ws_size,
                              hipStream_t stream) {
    const float* x  = (const float*)d_in[0];
    const float* W  = (const float*)d_in[1];
    const float* b  = (const float*)d_in[2];
    const float* ea = (const float*)d_in[3];

    float* out    = (float*)d_out;
    float* y_out  = out;                        // [D]
    float* W2_out = out + D;                    // [D*D]
    float* ea_out = out + D + (size_t)D * D;    // [D]

    float* ws  = (float*)d_ws;
    float* u   = ws;                            // [D]
    float* gfp = ws + D;                        // [D]
    float* gfn = ws + 2 * D;                    // [D]
    float* P   = ws + 3 * D;                    // [NCHUNK * D] = 2 MB

    k_gemv<<<D / 4, 256, 0, stream>>>(W, x, b, u);
    k_stats<<<1, 1024, 0, stream>>>(u, ea, y_out, ea_out, gfp, gfn);
    dim3 grid(NCOLTILE, NCHUNK);
    k_partial<<<grid, TPB, 0, stream>>>(W, y_out, P);
    k_scan<<<D / TPB, TPB, 0, stream>>>(P);
    k_update<<<grid, TPB, 0, stream>>>(W, x, y_out, P, gfp, gfn, W2_out);
}